// Round 4
// baseline (1030.324 us; speedup 1.0000x reference)
//
#include <hip/hip_runtime.h>
#include <hip/hip_bf16.h>

#define CDIM 256
#define NH 8
#define HDIM 32

typedef short bf8 __attribute__((ext_vector_type(8)));
typedef float f32x4 __attribute__((ext_vector_type(4)));

__device__ __forceinline__ float bf2f(ushort u) {
  union { unsigned int i; float f; } x; x.i = ((unsigned int)u) << 16; return x.f;
}
__device__ __forceinline__ ushort f2bf(float f) {
  union { float f; unsigned int i; } x; x.f = f;
  unsigned int lsb = (x.i >> 16) & 1u;
  unsigned int r = x.i + 0x7fffu + lsb;
  return (ushort)(r >> 16);
}

// ---------------- casts fp32 -> bf16 (vectorized) ----------------
__global__ void k_cast4(const float4* __restrict__ s, ushort4* __restrict__ d, int n4) {
  int i = blockIdx.x * blockDim.x + threadIdx.x;
  if (i < n4) {
    float4 v = s[i];
    ushort4 o;
    o.x = f2bf(v.x); o.y = f2bf(v.y); o.z = f2bf(v.z); o.w = f2bf(v.w);
    d[i] = o;
  }
}

// ---------------- CSR build ----------------
__global__ void k_hist(const int* __restrict__ dst, int E, int* __restrict__ deg) {
  int i = blockIdx.x * blockDim.x + threadIdx.x;
  if (i < E) atomicAdd(&deg[dst[i]], 1);
}

__global__ __launch_bounds__(1024) void k_scan1(const int* __restrict__ deg, int N,
                                                int* __restrict__ rowptr, int* __restrict__ bsum) {
  __shared__ int s[1024];
  int t = threadIdx.x;
  int i = blockIdx.x * 1024 + t;
  int val = (i < N) ? deg[i] : 0;
  s[t] = val;
  __syncthreads();
  for (int off = 1; off < 1024; off <<= 1) {
    int add = (t >= off) ? s[t - off] : 0;
    __syncthreads();
    s[t] += add;
    __syncthreads();
  }
  if (i < N) rowptr[i + 1] = s[t];
  if (t == 1023) bsum[blockIdx.x] = s[t];
}

__global__ void k_scan2(int* __restrict__ bsum, int nb) {
  if (threadIdx.x == 0 && blockIdx.x == 0) {
    int run = 0;
    for (int j = 0; j < nb; ++j) { int t = bsum[j]; bsum[j] = run; run += t; }
  }
}

__global__ void k_scan3(int* __restrict__ rowptr, const int* __restrict__ bsum, int N) {
  int i = blockIdx.x * blockDim.x + threadIdx.x;
  if (i < N) rowptr[i + 1] += bsum[i >> 10];
  if (i == 0) rowptr[0] = 0;
}

__global__ void k_scatter(const int* __restrict__ src, const int* __restrict__ dst, int E,
                          const int* __restrict__ rowptr, int* __restrict__ cur,
                          int* __restrict__ csr_src) {
  int i = blockIdx.x * blockDim.x + threadIdx.x;
  if (i < E) {
    int d = dst[i];
    int pos = rowptr[d] + atomicAdd(&cur[d], 1);
    csr_src[pos] = src[i];
  }
}

// ---------------- GEMM tiles (bf16 MFMA 16x16x32) ----------------
// 64x64/wave, A global row-major (row-clamped), B = W [out,in] row-major (acts B^T).
__device__ __forceinline__ void wave_tile64(const ushort* __restrict__ A, int lda, int row0, int nrows,
                                            const ushort* __restrict__ B, int ldb, int col0,
                                            int K, f32x4* acc) {
  int lane = threadIdx.x & 63;
  int m = lane & 15, quad = lane >> 4;
  const ushort* ap[4];
  const ushort* bp[4];
#pragma unroll
  for (int ri = 0; ri < 4; ++ri) {
    int r = row0 + ri * 16 + m;
    r = (r < nrows) ? r : (nrows - 1);
    ap[ri] = A + (size_t)r * lda + quad * 8;
  }
#pragma unroll
  for (int cj = 0; cj < 4; ++cj)
    bp[cj] = B + (size_t)(col0 + cj * 16 + m) * ldb + quad * 8;
  for (int k0 = 0; k0 < K; k0 += 32) {
    bf8 a[4], b[4];
#pragma unroll
    for (int ri = 0; ri < 4; ++ri) a[ri] = *(const bf8*)(ap[ri] + k0);
#pragma unroll
    for (int cj = 0; cj < 4; ++cj) b[cj] = *(const bf8*)(bp[cj] + k0);
#pragma unroll
    for (int ri = 0; ri < 4; ++ri)
#pragma unroll
      for (int cj = 0; cj < 4; ++cj)
        acc[ri * 4 + cj] = __builtin_amdgcn_mfma_f32_16x16x32_bf16(a[ri], b[cj], acc[ri * 4 + cj], 0, 0, 0);
  }
}

// 32-row variant (ri in 0..1), A global
__device__ __forceinline__ void wave_tile32g(const ushort* __restrict__ A, int lda, int row0, int nrows,
                                             const ushort* __restrict__ B, int ldb, int col0,
                                             int K, f32x4* acc) {
  int lane = threadIdx.x & 63;
  int m = lane & 15, quad = lane >> 4;
  const ushort* ap[2];
  const ushort* bp[4];
#pragma unroll
  for (int ri = 0; ri < 2; ++ri) {
    int r = row0 + ri * 16 + m;
    r = (r < nrows) ? r : (nrows - 1);
    ap[ri] = A + (size_t)r * lda + quad * 8;
  }
#pragma unroll
  for (int cj = 0; cj < 4; ++cj)
    bp[cj] = B + (size_t)(col0 + cj * 16 + m) * ldb + quad * 8;
  for (int k0 = 0; k0 < K; k0 += 32) {
    bf8 a[2], b[4];
#pragma unroll
    for (int ri = 0; ri < 2; ++ri) a[ri] = *(const bf8*)(ap[ri] + k0);
#pragma unroll
    for (int cj = 0; cj < 4; ++cj) b[cj] = *(const bf8*)(bp[cj] + k0);
#pragma unroll
    for (int ri = 0; ri < 2; ++ri)
#pragma unroll
      for (int cj = 0; cj < 4; ++cj)
        acc[ri * 4 + cj] = __builtin_amdgcn_mfma_f32_16x16x32_bf16(a[ri], b[cj], acc[ri * 4 + cj], 0, 0, 0);
  }
}

// q,k,v for 64 rows per block; feat (fp32) staged once into XOR-swizzled LDS as bf16.
__global__ __launch_bounds__(256) void k_qkv(const float* __restrict__ feat,
                                             const ushort* __restrict__ Wq, const ushort* __restrict__ Wk,
                                             const ushort* __restrict__ Wv,
                                             const float* __restrict__ bq, const float* __restrict__ bk,
                                             const float* __restrict__ bv,
                                             ushort* __restrict__ q, ushort* __restrict__ k,
                                             ushort* __restrict__ v, int N) {
  __shared__ ushort sa[64 * 256];  // 32 KB
  int rt = blockIdx.x, row0 = rt * 64;
  // stage 64x256 fp32 -> bf16 swizzled: 2048 16B granules, 8 per thread
#pragma unroll
  for (int s = 0; s < 8; ++s) {
    int c = threadIdx.x + s * 256;
    int row = c >> 5, g = c & 31;
    int r = row0 + row; r = (r < N) ? r : (N - 1);
    const float* fp = feat + (size_t)r * CDIM + g * 8;
    float4 x0 = *(const float4*)fp;
    float4 x1 = *(const float4*)(fp + 4);
    union { ushort us[8]; uint4 v; } pk;
    pk.us[0] = f2bf(x0.x); pk.us[1] = f2bf(x0.y); pk.us[2] = f2bf(x0.z); pk.us[3] = f2bf(x0.w);
    pk.us[4] = f2bf(x1.x); pk.us[5] = f2bf(x1.y); pk.us[6] = f2bf(x1.z); pk.us[7] = f2bf(x1.w);
    *(uint4*)&sa[row * 256 + ((g ^ (row & 7)) << 3)] = pk.v;
  }
  __syncthreads();

  int wave = threadIdx.x >> 6, lane = threadIdx.x & 63, m = lane & 15, quad = lane >> 4;
  int col0 = wave * 64;
  for (int which = 0; which < 3; ++which) {
    const ushort* W = (which == 0) ? Wq : (which == 1) ? Wk : Wv;
    const float* bias = (which == 0) ? bq : (which == 1) ? bk : bv;
    ushort* outp = (which == 0) ? q : (which == 1) ? k : v;
    f32x4 acc[16];
#pragma unroll
    for (int j = 0; j < 16; ++j) acc[j] = (f32x4){0.f, 0.f, 0.f, 0.f};
    const ushort* bp[4];
#pragma unroll
    for (int cj = 0; cj < 4; ++cj)
      bp[cj] = W + (size_t)(col0 + cj * 16 + m) * CDIM + quad * 8;
    for (int k0 = 0; k0 < CDIM; k0 += 32) {
      int sw = ((((k0 >> 3) + quad) ^ (m & 7)) << 3);
      bf8 a[4], b[4];
#pragma unroll
      for (int ri = 0; ri < 4; ++ri) a[ri] = *(const bf8*)&sa[(ri * 16 + m) * 256 + sw];
#pragma unroll
      for (int cj = 0; cj < 4; ++cj) b[cj] = *(const bf8*)(bp[cj] + k0);
#pragma unroll
      for (int ri = 0; ri < 4; ++ri)
#pragma unroll
        for (int cj = 0; cj < 4; ++cj)
          acc[ri * 4 + cj] = __builtin_amdgcn_mfma_f32_16x16x32_bf16(a[ri], b[cj], acc[ri * 4 + cj], 0, 0, 0);
    }
#pragma unroll
    for (int cj = 0; cj < 4; ++cj) {
      int cc = col0 + cj * 16 + m;
      float bs = bias[cc];
#pragma unroll
      for (int ri = 0; ri < 4; ++ri)
#pragma unroll
        for (int i = 0; i < 4; ++i) {
          int r = row0 + ri * 16 + quad * 4 + i;
          if (r < N) outp[(size_t)r * CDIM + cc] = f2bf(acc[ri * 4 + cj][i] + bs);
        }
    }
  }
}

// fused segment softmax + aggregate (unchanged from round 3)
__global__ __launch_bounds__(256) void k_edge_agg(const ushort* __restrict__ q,
                                                  const ushort* __restrict__ kk,
                                                  const ushort* __restrict__ vv,
                                                  const int* __restrict__ rowptr,
                                                  const int* __restrict__ csr_src,
                                                  int N,
                                                  ushort* __restrict__ wv) {
  __shared__ float e_T[8 * 36];
  __shared__ int srcs[32];
  __shared__ float wdens[32];

  int n = blockIdx.x;
  int t = threadIdx.x;
  int lane = t & 63, wave = t >> 6;
  int el = t >> 3, h = t & 7;
  int h2 = t >> 5;

  int beg = rowptr[n], end = rowptr[n + 1];
  int deg = end - beg;

  float qf[32];
  {
    const ushort* qp = q + (size_t)n * CDIM + h * HDIM;
#pragma unroll
    for (int g = 0; g < 4; ++g) {
      bf8 qv = *(const bf8*)(qp + g * 8);
#pragma unroll
      for (int j = 0; j < 8; ++j) qf[g * 8 + j] = bf2f((ushort)qv[j]);
    }
  }

  float accv = 0.f;
  float den_part = 0.f;

  int nch = (deg + 31) >> 5;
  for (int ch = 0; ch < nch; ++ch) {
    int eidx = beg + ch * 32 + el;
    int src = 0;
    float e = 0.f;
    if (eidx < end) {
      src = csr_src[eidx];
      const ushort* kp = kk + (size_t)src * CDIM + h * HDIM;
      float dot = 0.f;
#pragma unroll
      for (int g = 0; g < 4; ++g) {
        bf8 kv = *(const bf8*)(kp + g * 8);
#pragma unroll
        for (int j = 0; j < 8; ++j) dot = fmaf(qf[g * 8 + j], bf2f((ushort)kv[j]), dot);
      }
      float s = dot * 0.17677669529663687f;
      s = fminf(10.f, fmaxf(-10.f, s));
      e = __expf(s - 10.f);
    }
    e_T[h * 36 + el] = e;
    if (h == 0) srcs[el] = src;
    den_part += e;
    __syncthreads();

#pragma unroll
    for (int g4 = 0; g4 < 8; ++g4) {
      int4 s4 = *(const int4*)&srcs[g4 * 4];
      float4 e4 = *(const float4*)&e_T[h2 * 36 + g4 * 4];
      accv = fmaf(e4.x, bf2f(vv[(size_t)s4.x * CDIM + t]), accv);
      accv = fmaf(e4.y, bf2f(vv[(size_t)s4.y * CDIM + t]), accv);
      accv = fmaf(e4.z, bf2f(vv[(size_t)s4.z * CDIM + t]), accv);
      accv = fmaf(e4.w, bf2f(vv[(size_t)s4.w * CDIM + t]), accv);
    }
    __syncthreads();
  }

  float d = den_part;
  d += __shfl_xor(d, 8);
  d += __shfl_xor(d, 16);
  d += __shfl_xor(d, 32);
  if (lane < 8) wdens[wave * 8 + lane] = d;
  __syncthreads();
  float den = wdens[h2] + wdens[8 + h2] + wdens[16 + h2] + wdens[24 + h2];
  wv[(size_t)n * CDIM + t] = f2bf((deg > 0) ? accv / den : 0.f);
}

// x = feat + wv@Wp^T + bp, then h = LN(x)*g + b, fused (block owns full 64 rows x 256 cols)
__global__ __launch_bounds__(256) void k_proj_ln(const ushort* __restrict__ wv,
                                                 const ushort* __restrict__ Wp,
                                                 const float* __restrict__ bp,
                                                 const float* __restrict__ feat,
                                                 float* __restrict__ x,
                                                 const float* __restrict__ lng,
                                                 const float* __restrict__ lnb,
                                                 ushort* __restrict__ h, int N) {
  __shared__ float red_s[64 * 4];
  __shared__ float red_ss[64 * 4];
  __shared__ float stats[64 * 2];
  int rt = blockIdx.x;
  int wave = threadIdx.x >> 6, lane = threadIdx.x & 63, m = lane & 15, quad = lane >> 4;
  int row0 = rt * 64, col0 = wave * 64;
  f32x4 acc[16];
#pragma unroll
  for (int j = 0; j < 16; ++j) acc[j] = (f32x4){0.f, 0.f, 0.f, 0.f};
  wave_tile64(wv, CDIM, row0, N, Wp, CDIM, col0, CDIM, acc);

  float s1[4][4], s2[4][4];
#pragma unroll
  for (int ri = 0; ri < 4; ++ri)
#pragma unroll
    for (int i = 0; i < 4; ++i) { s1[ri][i] = 0.f; s2[ri][i] = 0.f; }

#pragma unroll
  for (int cj = 0; cj < 4; ++cj) {
    int cc = col0 + cj * 16 + m;
    float bs = bp[cc];
#pragma unroll
    for (int ri = 0; ri < 4; ++ri)
#pragma unroll
      for (int i = 0; i < 4; ++i) {
        int r = row0 + ri * 16 + quad * 4 + i;
        if (r < N) {
          float val = acc[ri * 4 + cj][i] + bs + feat[(size_t)r * CDIM + cc];
          acc[ri * 4 + cj][i] = val;
          x[(size_t)r * CDIM + cc] = val;
          s1[ri][i] += val;
          s2[ri][i] += val * val;
        }
      }
  }
  // reduce over the 16 m-lanes within each quad
#pragma unroll
  for (int msk = 1; msk <= 8; msk <<= 1) {
#pragma unroll
    for (int ri = 0; ri < 4; ++ri)
#pragma unroll
      for (int i = 0; i < 4; ++i) {
        s1[ri][i] += __shfl_xor(s1[ri][i], msk);
        s2[ri][i] += __shfl_xor(s2[ri][i], msk);
      }
  }
  if (m == 0) {
#pragma unroll
    for (int ri = 0; ri < 4; ++ri)
#pragma unroll
      for (int i = 0; i < 4; ++i) {
        int lr = ri * 16 + quad * 4 + i;
        red_s[lr * 4 + wave] = s1[ri][i];
        red_ss[lr * 4 + wave] = s2[ri][i];
      }
  }
  __syncthreads();
  if (threadIdx.x < 64) {
    int lr = threadIdx.x;
    float s = red_s[lr * 4] + red_s[lr * 4 + 1] + red_s[lr * 4 + 2] + red_s[lr * 4 + 3];
    float ss = red_ss[lr * 4] + red_ss[lr * 4 + 1] + red_ss[lr * 4 + 2] + red_ss[lr * 4 + 3];
    float mu = s * (1.f / CDIM);
    float var = ss * (1.f / CDIM) - mu * mu;
    stats[lr * 2] = mu;
    stats[lr * 2 + 1] = rsqrtf(var + 1e-5f);
  }
  __syncthreads();
#pragma unroll
  for (int cj = 0; cj < 4; ++cj) {
    int cc = col0 + cj * 16 + m;
    float ga = lng[cc], be = lnb[cc];
#pragma unroll
    for (int ri = 0; ri < 4; ++ri)
#pragma unroll
      for (int i = 0; i < 4; ++i) {
        int lr = ri * 16 + quad * 4 + i;
        int r = row0 + lr;
        if (r < N) {
          float mu = stats[lr * 2], rs = stats[lr * 2 + 1];
          h[(size_t)r * CDIM + cc] = f2bf((acc[ri * 4 + cj][i] - mu) * rs * ga + be);
        }
      }
  }
}

// fused MLP: out = x + gelu(h@W1^T+b1)@W2^T + b2. 512 threads / 8 waves, 32 rows/block,
// hidden 32x1024 bf16 XOR-swizzled in 64 KB LDS. 2 blocks/CU -> 16 waves/CU.
#define SHST 1024
__global__ __launch_bounds__(512) void k_mlp(const ushort* __restrict__ h,
                                             const ushort* __restrict__ W1,
                                             const float* __restrict__ b1,
                                             const ushort* __restrict__ W2,
                                             const float* __restrict__ b2,
                                             const float* __restrict__ x,
                                             float* __restrict__ out, int N) {
  __shared__ ushort sh[32 * SHST];  // 64 KB
  int rt = blockIdx.x;
  int row0 = rt * 32;
  int wave = threadIdx.x >> 6, lane = threadIdx.x & 63, m = lane & 15, quad = lane >> 4;

  // phase 1: wave computes hidden cols [wave*128, +128) as 2 tiles of 32x64
  for (int cg = 0; cg < 2; ++cg) {
    int col0 = wave * 128 + cg * 64;
    f32x4 acc[8];
#pragma unroll
    for (int j = 0; j < 8; ++j) acc[j] = (f32x4){0.f, 0.f, 0.f, 0.f};
    wave_tile32g(h, CDIM, row0, N, W1, CDIM, col0, CDIM, acc);
#pragma unroll
    for (int cj = 0; cj < 4; ++cj) {
      int cc = col0 + cj * 16 + m;
      float bs = b1[cc];
#pragma unroll
      for (int ri = 0; ri < 2; ++ri)
#pragma unroll
        for (int i = 0; i < 4; ++i) {
          int lr = ri * 16 + quad * 4 + i;
          float tt = acc[ri * 4 + cj][i] + bs;
          float gl = 0.5f * tt * (1.f + erff(tt * 0.70710678118654752f));
          int sc = ((((cc >> 3) ^ (lr & 7)) << 3) | (cc & 7));
          sh[lr * SHST + sc] = f2bf(gl);
        }
    }
  }
  __syncthreads();

  // phase 2: wave computes out cols [wave*32, +32), K=1024 from swizzled LDS
  int col0 = wave * 32;
  f32x4 acc[4];
#pragma unroll
  for (int j = 0; j < 4; ++j) acc[j] = (f32x4){0.f, 0.f, 0.f, 0.f};
  const ushort* bp[2];
#pragma unroll
  for (int cj = 0; cj < 2; ++cj)
    bp[cj] = W2 + (size_t)(col0 + cj * 16 + m) * 1024 + quad * 8;
  for (int k0 = 0; k0 < 1024; k0 += 32) {
    int sw = ((((k0 >> 3) + quad) ^ (m & 7)) << 3);
    bf8 a[2], b[2];
#pragma unroll
    for (int ri = 0; ri < 2; ++ri) a[ri] = *(const bf8*)&sh[(ri * 16 + m) * SHST + sw];
#pragma unroll
    for (int cj = 0; cj < 2; ++cj) b[cj] = *(const bf8*)(bp[cj] + k0);
#pragma unroll
    for (int ri = 0; ri < 2; ++ri)
#pragma unroll
      for (int cj = 0; cj < 2; ++cj)
        acc[ri * 2 + cj] = __builtin_amdgcn_mfma_f32_16x16x32_bf16(a[ri], b[cj], acc[ri * 2 + cj], 0, 0, 0);
  }
#pragma unroll
  for (int cj = 0; cj < 2; ++cj) {
    int cc = col0 + cj * 16 + m;
    float bs = b2[cc];
#pragma unroll
    for (int ri = 0; ri < 2; ++ri)
#pragma unroll
      for (int i = 0; i < 4; ++i) {
        int r = row0 + ri * 16 + quad * 4 + i;
        if (r < N) out[(size_t)r * CDIM + cc] = x[(size_t)r * CDIM + cc] + acc[ri * 2 + cj][i] + bs;
      }
  }
}

extern "C" void kernel_launch(void* const* d_in, const int* in_sizes, int n_in,
                              void* d_out, int out_size, void* d_ws, size_t ws_size,
                              hipStream_t stream) {
  const float* feat = (const float*)d_in[0];
  const int* esrc = (const int*)d_in[1];
  const int* edst = (const int*)d_in[2];
  const float* Wq = (const float*)d_in[3];
  const float* bq = (const float*)d_in[4];
  const float* Wk = (const float*)d_in[5];
  const float* bk = (const float*)d_in[6];
  const float* Wv = (const float*)d_in[7];
  const float* bv = (const float*)d_in[8];
  const float* Wp = (const float*)d_in[9];
  const float* bp = (const float*)d_in[10];
  const float* lng = (const float*)d_in[11];
  const float* lnb = (const float*)d_in[12];
  const float* W1 = (const float*)d_in[13];
  const float* b1 = (const float*)d_in[14];
  const float* W2 = (const float*)d_in[15];
  const float* b2 = (const float*)d_in[16];

  const int N = in_sizes[0] / CDIM;  // 50000
  const int E = in_sizes[1];         // 1600000
  const size_t NC2 = (size_t)N * CDIM * 2;  // bf16 plane: 25.6 MB

  char* w = (char*)d_ws;
  ushort* q   = (ushort*)(w);
  ushort* kk  = (ushort*)(w + NC2);
  ushort* vv  = (ushort*)(w + 2 * NC2);
  ushort* wvb = (ushort*)(w + 3 * NC2);
  float*  x   = (float*)(w);               // overlays q+k (dead after edge_agg)
  ushort* h   = (ushort*)(w + 2 * NC2);    // overlays v (dead after edge_agg)

  char* csr = w + 4 * NC2;
  int* rowptr  = (int*)(csr);
  int* deg     = (int*)(csr + 200064);
  int* csr_src = (int*)(csr + 400128);
  int* bsum    = (int*)(csr + 400128 + (size_t)E * 4);

  char* wb = csr + 400128 + (size_t)E * 4 + 256;
  ushort* Wqb = (ushort*)(wb);
  ushort* Wkb = (ushort*)(wb + 131072);
  ushort* Wvb = (ushort*)(wb + 262144);
  ushort* Wpb = (ushort*)(wb + 393216);
  ushort* W1b = (ushort*)(wb + 524288);
  ushort* W2b = (ushort*)(wb + 1048576);

  const int nb = (N + 1023) / 1024;
  const int RT64 = (N + 63) / 64;   // 782
  const int RT32 = (N + 31) / 32;   // 1563

  // weight casts
  k_cast4<<<(16384 + 255) / 256, 256, 0, stream>>>((const float4*)Wq, (ushort4*)Wqb, 16384);
  k_cast4<<<(16384 + 255) / 256, 256, 0, stream>>>((const float4*)Wk, (ushort4*)Wkb, 16384);
  k_cast4<<<(16384 + 255) / 256, 256, 0, stream>>>((const float4*)Wv, (ushort4*)Wvb, 16384);
  k_cast4<<<(16384 + 255) / 256, 256, 0, stream>>>((const float4*)Wp, (ushort4*)Wpb, 16384);
  k_cast4<<<(65536 + 255) / 256, 256, 0, stream>>>((const float4*)W1, (ushort4*)W1b, 65536);
  k_cast4<<<(65536 + 255) / 256, 256, 0, stream>>>((const float4*)W2, (ushort4*)W2b, 65536);

  // CSR build (group edges by dst)
  hipMemsetAsync(deg, 0, (size_t)N * 4, stream);
  k_hist<<<(E + 255) / 256, 256, 0, stream>>>(edst, E, deg);
  k_scan1<<<nb, 1024, 0, stream>>>(deg, N, rowptr, bsum);
  k_scan2<<<1, 64, 0, stream>>>(bsum, nb);
  k_scan3<<<(N + 255) / 256, 256, 0, stream>>>(rowptr, bsum, N);
  hipMemsetAsync(deg, 0, (size_t)N * 4, stream);
  k_scatter<<<(E + 255) / 256, 256, 0, stream>>>(esrc, edst, E, rowptr, deg, csr_src);

  // QKV projections (feat converted inline in LDS staging)
  k_qkv<<<RT64, 256, 0, stream>>>(feat, Wqb, Wkb, Wvb, bq, bk, bv, q, kk, vv, N);
  // fused segment-softmax + aggregate
  k_edge_agg<<<N, 256, 0, stream>>>(q, kk, vv, rowptr, csr_src, N, wvb);
  // x = feat + wv@Wp^T + bp ; h = LN(x) (fused)
  k_proj_ln<<<RT64, 256, 0, stream>>>(wvb, Wpb, bp, feat, x, lng, lnb, h, N);
  // out = x + gelu(h@W1^T+b1)@W2^T + b2 (fused through LDS)
  k_mlp<<<RT32, 512, 0, stream>>>(h, W1b, b1, W2b, b2, x, (float*)d_out, N);
}

// Round 5
// 1028.499 us; speedup vs baseline: 1.0018x; 1.0018x over previous
//
#include <hip/hip_runtime.h>
#include <hip/hip_bf16.h>

#define CDIM 256
#define NH 8
#define HDIM 32

typedef short bf8 __attribute__((ext_vector_type(8)));
typedef float f32x4 __attribute__((ext_vector_type(4)));

__device__ __forceinline__ float bf2f(ushort u) {
  union { unsigned int i; float f; } x; x.i = ((unsigned int)u) << 16; return x.f;
}
__device__ __forceinline__ ushort f2bf(float f) {
  union { float f; unsigned int i; } x; x.f = f;
  unsigned int lsb = (x.i >> 16) & 1u;
  unsigned int r = x.i + 0x7fffu + lsb;
  return (ushort)(r >> 16);
}

// ---------------- casts fp32 -> bf16 (vectorized) ----------------
__global__ void k_cast4(const float4* __restrict__ s, ushort4* __restrict__ d, int n4) {
  int i = blockIdx.x * blockDim.x + threadIdx.x;
  if (i < n4) {
    float4 v = s[i];
    ushort4 o;
    o.x = f2bf(v.x); o.y = f2bf(v.y); o.z = f2bf(v.z); o.w = f2bf(v.w);
    d[i] = o;
  }
}

// ---------------- CSR build ----------------
__global__ void k_hist(const int* __restrict__ dst, int E, int* __restrict__ deg) {
  int i = blockIdx.x * blockDim.x + threadIdx.x;
  if (i < E) atomicAdd(&deg[dst[i]], 1);
}

__global__ __launch_bounds__(1024) void k_scan1(const int* __restrict__ deg, int N,
                                                int* __restrict__ rowptr, int* __restrict__ bsum) {
  __shared__ int s[1024];
  int t = threadIdx.x;
  int i = blockIdx.x * 1024 + t;
  int val = (i < N) ? deg[i] : 0;
  s[t] = val;
  __syncthreads();
  for (int off = 1; off < 1024; off <<= 1) {
    int add = (t >= off) ? s[t - off] : 0;
    __syncthreads();
    s[t] += add;
    __syncthreads();
  }
  if (i < N) rowptr[i + 1] = s[t];
  if (t == 1023) bsum[blockIdx.x] = s[t];
}

__global__ void k_scan2(int* __restrict__ bsum, int nb) {
  if (threadIdx.x == 0 && blockIdx.x == 0) {
    int run = 0;
    for (int j = 0; j < nb; ++j) { int t = bsum[j]; bsum[j] = run; run += t; }
  }
}

__global__ void k_scan3(int* __restrict__ rowptr, const int* __restrict__ bsum, int N) {
  int i = blockIdx.x * blockDim.x + threadIdx.x;
  if (i < N) rowptr[i + 1] += bsum[i >> 10];
  if (i == 0) rowptr[0] = 0;
}

__global__ void k_scatter(const int* __restrict__ src, const int* __restrict__ dst, int E,
                          const int* __restrict__ rowptr, int* __restrict__ cur,
                          int* __restrict__ csr_src) {
  int i = blockIdx.x * blockDim.x + threadIdx.x;
  if (i < E) {
    int d = dst[i];
    int pos = rowptr[d] + atomicAdd(&cur[d], 1);
    csr_src[pos] = src[i];
  }
}

// ---------------- GEMM tiles (bf16 MFMA 16x16x32) ----------------
// 64x64/wave, A global row-major (row-clamped), B = W [out,in] row-major (acts B^T).
__device__ __forceinline__ void wave_tile64(const ushort* __restrict__ A, int lda, int row0, int nrows,
                                            const ushort* __restrict__ B, int ldb, int col0,
                                            int K, f32x4* acc) {
  int lane = threadIdx.x & 63;
  int m = lane & 15, quad = lane >> 4;
  const ushort* ap[4];
  const ushort* bp[4];
#pragma unroll
  for (int ri = 0; ri < 4; ++ri) {
    int r = row0 + ri * 16 + m;
    r = (r < nrows) ? r : (nrows - 1);
    ap[ri] = A + (size_t)r * lda + quad * 8;
  }
#pragma unroll
  for (int cj = 0; cj < 4; ++cj)
    bp[cj] = B + (size_t)(col0 + cj * 16 + m) * ldb + quad * 8;
  for (int k0 = 0; k0 < K; k0 += 32) {
    bf8 a[4], b[4];
#pragma unroll
    for (int ri = 0; ri < 4; ++ri) a[ri] = *(const bf8*)(ap[ri] + k0);
#pragma unroll
    for (int cj = 0; cj < 4; ++cj) b[cj] = *(const bf8*)(bp[cj] + k0);
#pragma unroll
    for (int ri = 0; ri < 4; ++ri)
#pragma unroll
      for (int cj = 0; cj < 4; ++cj)
        acc[ri * 4 + cj] = __builtin_amdgcn_mfma_f32_16x16x32_bf16(a[ri], b[cj], acc[ri * 4 + cj], 0, 0, 0);
  }
}

// 32-row variant (ri in 0..1), A global
__device__ __forceinline__ void wave_tile32g(const ushort* __restrict__ A, int lda, int row0, int nrows,
                                             const ushort* __restrict__ B, int ldb, int col0,
                                             int K, f32x4* acc) {
  int lane = threadIdx.x & 63;
  int m = lane & 15, quad = lane >> 4;
  const ushort* ap[2];
  const ushort* bp[4];
#pragma unroll
  for (int ri = 0; ri < 2; ++ri) {
    int r = row0 + ri * 16 + m;
    r = (r < nrows) ? r : (nrows - 1);
    ap[ri] = A + (size_t)r * lda + quad * 8;
  }
#pragma unroll
  for (int cj = 0; cj < 4; ++cj)
    bp[cj] = B + (size_t)(col0 + cj * 16 + m) * ldb + quad * 8;
  for (int k0 = 0; k0 < K; k0 += 32) {
    bf8 a[2], b[4];
#pragma unroll
    for (int ri = 0; ri < 2; ++ri) a[ri] = *(const bf8*)(ap[ri] + k0);
#pragma unroll
    for (int cj = 0; cj < 4; ++cj) b[cj] = *(const bf8*)(bp[cj] + k0);
#pragma unroll
    for (int ri = 0; ri < 2; ++ri)
#pragma unroll
      for (int cj = 0; cj < 4; ++cj)
        acc[ri * 4 + cj] = __builtin_amdgcn_mfma_f32_16x16x32_bf16(a[ri], b[cj], acc[ri * 4 + cj], 0, 0, 0);
  }
}

// q,k,v for 64 rows per block; feat (fp32) staged once into XOR-swizzled LDS as bf16.
__global__ __launch_bounds__(256) void k_qkv(const float* __restrict__ feat,
                                             const ushort* __restrict__ Wq, const ushort* __restrict__ Wk,
                                             const ushort* __restrict__ Wv,
                                             const float* __restrict__ bq, const float* __restrict__ bk,
                                             const float* __restrict__ bv,
                                             ushort* __restrict__ q, ushort* __restrict__ k,
                                             ushort* __restrict__ v, int N) {
  __shared__ ushort sa[64 * 256];  // 32 KB
  int rt = blockIdx.x, row0 = rt * 64;
#pragma unroll
  for (int s = 0; s < 8; ++s) {
    int c = threadIdx.x + s * 256;
    int row = c >> 5, g = c & 31;
    int r = row0 + row; r = (r < N) ? r : (N - 1);
    const float* fp = feat + (size_t)r * CDIM + g * 8;
    float4 x0 = *(const float4*)fp;
    float4 x1 = *(const float4*)(fp + 4);
    union { ushort us[8]; uint4 v; } pk;
    pk.us[0] = f2bf(x0.x); pk.us[1] = f2bf(x0.y); pk.us[2] = f2bf(x0.z); pk.us[3] = f2bf(x0.w);
    pk.us[4] = f2bf(x1.x); pk.us[5] = f2bf(x1.y); pk.us[6] = f2bf(x1.z); pk.us[7] = f2bf(x1.w);
    *(uint4*)&sa[row * 256 + ((g ^ (row & 7)) << 3)] = pk.v;
  }
  __syncthreads();

  int wave = threadIdx.x >> 6, lane = threadIdx.x & 63, m = lane & 15, quad = lane >> 4;
  int col0 = wave * 64;
  for (int which = 0; which < 3; ++which) {
    const ushort* W = (which == 0) ? Wq : (which == 1) ? Wk : Wv;
    const float* bias = (which == 0) ? bq : (which == 1) ? bk : bv;
    ushort* outp = (which == 0) ? q : (which == 1) ? k : v;
    f32x4 acc[16];
#pragma unroll
    for (int j = 0; j < 16; ++j) acc[j] = (f32x4){0.f, 0.f, 0.f, 0.f};
    const ushort* bp[4];
#pragma unroll
    for (int cj = 0; cj < 4; ++cj)
      bp[cj] = W + (size_t)(col0 + cj * 16 + m) * CDIM + quad * 8;
    for (int k0 = 0; k0 < CDIM; k0 += 32) {
      int sw = ((((k0 >> 3) + quad) ^ (m & 7)) << 3);
      bf8 a[4], b[4];
#pragma unroll
      for (int ri = 0; ri < 4; ++ri) a[ri] = *(const bf8*)&sa[(ri * 16 + m) * 256 + sw];
#pragma unroll
      for (int cj = 0; cj < 4; ++cj) b[cj] = *(const bf8*)(bp[cj] + k0);
#pragma unroll
      for (int ri = 0; ri < 4; ++ri)
#pragma unroll
        for (int cj = 0; cj < 4; ++cj)
          acc[ri * 4 + cj] = __builtin_amdgcn_mfma_f32_16x16x32_bf16(a[ri], b[cj], acc[ri * 4 + cj], 0, 0, 0);
    }
#pragma unroll
    for (int cj = 0; cj < 4; ++cj) {
      int cc = col0 + cj * 16 + m;
      float bs = bias[cc];
#pragma unroll
      for (int ri = 0; ri < 4; ++ri)
#pragma unroll
        for (int i = 0; i < 4; ++i) {
          int r = row0 + ri * 16 + quad * 4 + i;
          if (r < N) outp[(size_t)r * CDIM + cc] = f2bf(acc[ri * 4 + cj][i] + bs);
        }
    }
  }
}

// fused segment softmax + aggregate (unchanged)
__global__ __launch_bounds__(256) void k_edge_agg(const ushort* __restrict__ q,
                                                  const ushort* __restrict__ kk,
                                                  const ushort* __restrict__ vv,
                                                  const int* __restrict__ rowptr,
                                                  const int* __restrict__ csr_src,
                                                  int N,
                                                  ushort* __restrict__ wv) {
  __shared__ float e_T[8 * 36];
  __shared__ int srcs[32];
  __shared__ float wdens[32];

  int n = blockIdx.x;
  int t = threadIdx.x;
  int lane = t & 63, wave = t >> 6;
  int el = t >> 3, h = t & 7;
  int h2 = t >> 5;

  int beg = rowptr[n], end = rowptr[n + 1];
  int deg = end - beg;

  float qf[32];
  {
    const ushort* qp = q + (size_t)n * CDIM + h * HDIM;
#pragma unroll
    for (int g = 0; g < 4; ++g) {
      bf8 qv = *(const bf8*)(qp + g * 8);
#pragma unroll
      for (int j = 0; j < 8; ++j) qf[g * 8 + j] = bf2f((ushort)qv[j]);
    }
  }

  float accv = 0.f;
  float den_part = 0.f;

  int nch = (deg + 31) >> 5;
  for (int ch = 0; ch < nch; ++ch) {
    int eidx = beg + ch * 32 + el;
    int src = 0;
    float e = 0.f;
    if (eidx < end) {
      src = csr_src[eidx];
      const ushort* kp = kk + (size_t)src * CDIM + h * HDIM;
      float dot = 0.f;
#pragma unroll
      for (int g = 0; g < 4; ++g) {
        bf8 kv = *(const bf8*)(kp + g * 8);
#pragma unroll
        for (int j = 0; j < 8; ++j) dot = fmaf(qf[g * 8 + j], bf2f((ushort)kv[j]), dot);
      }
      float s = dot * 0.17677669529663687f;
      s = fminf(10.f, fmaxf(-10.f, s));
      e = __expf(s - 10.f);
    }
    e_T[h * 36 + el] = e;
    if (h == 0) srcs[el] = src;
    den_part += e;
    __syncthreads();

#pragma unroll
    for (int g4 = 0; g4 < 8; ++g4) {
      int4 s4 = *(const int4*)&srcs[g4 * 4];
      float4 e4 = *(const float4*)&e_T[h2 * 36 + g4 * 4];
      accv = fmaf(e4.x, bf2f(vv[(size_t)s4.x * CDIM + t]), accv);
      accv = fmaf(e4.y, bf2f(vv[(size_t)s4.y * CDIM + t]), accv);
      accv = fmaf(e4.z, bf2f(vv[(size_t)s4.z * CDIM + t]), accv);
      accv = fmaf(e4.w, bf2f(vv[(size_t)s4.w * CDIM + t]), accv);
    }
    __syncthreads();
  }

  float d = den_part;
  d += __shfl_xor(d, 8);
  d += __shfl_xor(d, 16);
  d += __shfl_xor(d, 32);
  if (lane < 8) wdens[wave * 8 + lane] = d;
  __syncthreads();
  float den = wdens[h2] + wdens[8 + h2] + wdens[16 + h2] + wdens[24 + h2];
  wv[(size_t)n * CDIM + t] = f2bf((deg > 0) ? accv / den : 0.f);
}

// x = feat + wv@Wp^T + bp, then h = LN(x)*g + b, fused (block owns 64 rows x 256 cols)
__global__ __launch_bounds__(256) void k_proj_ln(const ushort* __restrict__ wv,
                                                 const ushort* __restrict__ Wp,
                                                 const float* __restrict__ bp,
                                                 const float* __restrict__ feat,
                                                 float* __restrict__ x,
                                                 const float* __restrict__ lng,
                                                 const float* __restrict__ lnb,
                                                 ushort* __restrict__ h, int N) {
  __shared__ float red_s[64 * 4];
  __shared__ float red_ss[64 * 4];
  __shared__ float stats[64 * 2];
  int rt = blockIdx.x;
  int wave = threadIdx.x >> 6, lane = threadIdx.x & 63, m = lane & 15, quad = lane >> 4;
  int row0 = rt * 64, col0 = wave * 64;
  f32x4 acc[16];
#pragma unroll
  for (int j = 0; j < 16; ++j) acc[j] = (f32x4){0.f, 0.f, 0.f, 0.f};
  wave_tile64(wv, CDIM, row0, N, Wp, CDIM, col0, CDIM, acc);

  float s1[4][4], s2[4][4];
#pragma unroll
  for (int ri = 0; ri < 4; ++ri)
#pragma unroll
    for (int i = 0; i < 4; ++i) { s1[ri][i] = 0.f; s2[ri][i] = 0.f; }

#pragma unroll
  for (int cj = 0; cj < 4; ++cj) {
    int cc = col0 + cj * 16 + m;
    float bs = bp[cc];
#pragma unroll
    for (int ri = 0; ri < 4; ++ri)
#pragma unroll
      for (int i = 0; i < 4; ++i) {
        int r = row0 + ri * 16 + quad * 4 + i;
        if (r < N) {
          float val = acc[ri * 4 + cj][i] + bs + feat[(size_t)r * CDIM + cc];
          acc[ri * 4 + cj][i] = val;
          x[(size_t)r * CDIM + cc] = val;
          s1[ri][i] += val;
          s2[ri][i] += val * val;
        }
      }
  }
#pragma unroll
  for (int msk = 1; msk <= 8; msk <<= 1) {
#pragma unroll
    for (int ri = 0; ri < 4; ++ri)
#pragma unroll
      for (int i = 0; i < 4; ++i) {
        s1[ri][i] += __shfl_xor(s1[ri][i], msk);
        s2[ri][i] += __shfl_xor(s2[ri][i], msk);
      }
  }
  if (m == 0) {
#pragma unroll
    for (int ri = 0; ri < 4; ++ri)
#pragma unroll
      for (int i = 0; i < 4; ++i) {
        int lr = ri * 16 + quad * 4 + i;
        red_s[lr * 4 + wave] = s1[ri][i];
        red_ss[lr * 4 + wave] = s2[ri][i];
      }
  }
  __syncthreads();
  if (threadIdx.x < 64) {
    int lr = threadIdx.x;
    float s = red_s[lr * 4] + red_s[lr * 4 + 1] + red_s[lr * 4 + 2] + red_s[lr * 4 + 3];
    float ss = red_ss[lr * 4] + red_ss[lr * 4 + 1] + red_ss[lr * 4 + 2] + red_ss[lr * 4 + 3];
    float mu = s * (1.f / CDIM);
    float var = ss * (1.f / CDIM) - mu * mu;
    stats[lr * 2] = mu;
    stats[lr * 2 + 1] = rsqrtf(var + 1e-5f);
  }
  __syncthreads();
#pragma unroll
  for (int cj = 0; cj < 4; ++cj) {
    int cc = col0 + cj * 16 + m;
    float ga = lng[cc], be = lnb[cc];
#pragma unroll
    for (int ri = 0; ri < 4; ++ri)
#pragma unroll
      for (int i = 0; i < 4; ++i) {
        int lr = ri * 16 + quad * 4 + i;
        int r = row0 + lr;
        if (r < N) {
          float mu = stats[lr * 2], rs = stats[lr * 2 + 1];
          h[(size_t)r * CDIM + cc] = f2bf((acc[ri * 4 + cj][i] - mu) * rs * ga + be);
        }
      }
  }
}

// fused MLP, K-slab version: out = x + gelu(h@W1^T+b1)@W2^T + b2.
// 32 rows/block, 256 thr (4 waves). Hidden processed in 4 slabs of 256 cols;
// each slab's 32x256 bf16 tile lives in 16 KB XOR-swizzled LDS. Phase-2
// accumulators persist across slabs. Small LDS -> many blocks/CU.
__global__ __launch_bounds__(256) void k_mlp(const ushort* __restrict__ h,
                                             const ushort* __restrict__ W1,
                                             const float* __restrict__ b1,
                                             const ushort* __restrict__ W2,
                                             const float* __restrict__ b2,
                                             const float* __restrict__ x,
                                             float* __restrict__ out, int N) {
  __shared__ ushort sh[32 * 256];  // 16 KB
  int rt = blockIdx.x;
  int row0 = rt * 32;
  int wave = threadIdx.x >> 6, lane = threadIdx.x & 63, m = lane & 15, quad = lane >> 4;

  int col0 = wave * 64;  // phase-2 out cols
  f32x4 acc2[8];
#pragma unroll
  for (int j = 0; j < 8; ++j) acc2[j] = (f32x4){0.f, 0.f, 0.f, 0.f};
  const ushort* bp2[4];
#pragma unroll
  for (int cj = 0; cj < 4; ++cj)
    bp2[cj] = W2 + (size_t)(col0 + cj * 16 + m) * 1024 + quad * 8;

  for (int slab = 0; slab < 4; ++slab) {
    // phase 1: this wave computes hidden cols [slab*256 + wave*64, +64)
    int hcol0 = slab * 256 + wave * 64;
    f32x4 acc1[8];
#pragma unroll
    for (int j = 0; j < 8; ++j) acc1[j] = (f32x4){0.f, 0.f, 0.f, 0.f};
    wave_tile32g(h, CDIM, row0, N, W1, CDIM, hcol0, CDIM, acc1);
#pragma unroll
    for (int cj = 0; cj < 4; ++cj) {
      int ccl = wave * 64 + cj * 16 + m;  // slab-local col
      float bs = b1[slab * 256 + ccl];
#pragma unroll
      for (int ri = 0; ri < 2; ++ri)
#pragma unroll
        for (int i = 0; i < 4; ++i) {
          int lr = ri * 16 + quad * 4 + i;
          float tt = acc1[ri * 4 + cj][i] + bs;
          float gl = 0.5f * tt * (1.f + erff(tt * 0.70710678118654752f));
          int sc = ((((ccl >> 3) ^ (lr & 7)) << 3) | (ccl & 7));
          sh[lr * 256 + sc] = f2bf(gl);
        }
    }
    __syncthreads();

    // phase 2: accumulate this slab's K=256 into persistent acc2
    for (int k0 = 0; k0 < 256; k0 += 32) {
      int g = (k0 >> 3) + quad;
      bf8 a[2], b[4];
#pragma unroll
      for (int ri = 0; ri < 2; ++ri)
        a[ri] = *(const bf8*)&sh[(ri * 16 + m) * 256 + ((g ^ (m & 7)) << 3)];
#pragma unroll
      for (int cj = 0; cj < 4; ++cj) b[cj] = *(const bf8*)(bp2[cj] + slab * 256 + k0);
#pragma unroll
      for (int ri = 0; ri < 2; ++ri)
#pragma unroll
        for (int cj = 0; cj < 4; ++cj)
          acc2[ri * 4 + cj] = __builtin_amdgcn_mfma_f32_16x16x32_bf16(a[ri], b[cj], acc2[ri * 4 + cj], 0, 0, 0);
    }
    __syncthreads();
  }

#pragma unroll
  for (int cj = 0; cj < 4; ++cj) {
    int cc = col0 + cj * 16 + m;
    float bs = b2[cc];
#pragma unroll
    for (int ri = 0; ri < 2; ++ri)
#pragma unroll
      for (int i = 0; i < 4; ++i) {
        int r = row0 + ri * 16 + quad * 4 + i;
        if (r < N) out[(size_t)r * CDIM + cc] = x[(size_t)r * CDIM + cc] + acc2[ri * 4 + cj][i] + bs;
      }
  }
}

extern "C" void kernel_launch(void* const* d_in, const int* in_sizes, int n_in,
                              void* d_out, int out_size, void* d_ws, size_t ws_size,
                              hipStream_t stream) {
  const float* feat = (const float*)d_in[0];
  const int* esrc = (const int*)d_in[1];
  const int* edst = (const int*)d_in[2];
  const float* Wq = (const float*)d_in[3];
  const float* bq = (const float*)d_in[4];
  const float* Wk = (const float*)d_in[5];
  const float* bk = (const float*)d_in[6];
  const float* Wv = (const float*)d_in[7];
  const float* bv = (const float*)d_in[8];
  const float* Wp = (const float*)d_in[9];
  const float* bp = (const float*)d_in[10];
  const float* lng = (const float*)d_in[11];
  const float* lnb = (const float*)d_in[12];
  const float* W1 = (const float*)d_in[13];
  const float* b1 = (const float*)d_in[14];
  const float* W2 = (const float*)d_in[15];
  const float* b2 = (const float*)d_in[16];

  const int N = in_sizes[0] / CDIM;  // 50000
  const int E = in_sizes[1];         // 1600000
  const size_t NC2 = (size_t)N * CDIM * 2;  // bf16 plane: 25.6 MB

  char* w = (char*)d_ws;
  ushort* q   = (ushort*)(w);
  ushort* kk  = (ushort*)(w + NC2);
  ushort* vv  = (ushort*)(w + 2 * NC2);
  ushort* wvb = (ushort*)(w + 3 * NC2);
  float*  x   = (float*)(w);               // overlays q+k (dead after edge_agg)
  ushort* h   = (ushort*)(w + 2 * NC2);    // overlays v (dead after edge_agg)

  char* csr = w + 4 * NC2;
  int* rowptr  = (int*)(csr);
  int* deg     = (int*)(csr + 200064);
  int* csr_src = (int*)(csr + 400128);
  int* bsum    = (int*)(csr + 400128 + (size_t)E * 4);

  char* wb = csr + 400128 + (size_t)E * 4 + 256;
  ushort* Wqb = (ushort*)(wb);
  ushort* Wkb = (ushort*)(wb + 131072);
  ushort* Wvb = (ushort*)(wb + 262144);
  ushort* Wpb = (ushort*)(wb + 393216);
  ushort* W1b = (ushort*)(wb + 524288);
  ushort* W2b = (ushort*)(wb + 1048576);

  const int nb = (N + 1023) / 1024;
  const int RT64 = (N + 63) / 64;   // 782
  const int RT32 = (N + 31) / 32;   // 1563

  // weight casts
  k_cast4<<<(16384 + 255) / 256, 256, 0, stream>>>((const float4*)Wq, (ushort4*)Wqb, 16384);
  k_cast4<<<(16384 + 255) / 256, 256, 0, stream>>>((const float4*)Wk, (ushort4*)Wkb, 16384);
  k_cast4<<<(16384 + 255) / 256, 256, 0, stream>>>((const float4*)Wv, (ushort4*)Wvb, 16384);
  k_cast4<<<(16384 + 255) / 256, 256, 0, stream>>>((const float4*)Wp, (ushort4*)Wpb, 16384);
  k_cast4<<<(65536 + 255) / 256, 256, 0, stream>>>((const float4*)W1, (ushort4*)W1b, 65536);
  k_cast4<<<(65536 + 255) / 256, 256, 0, stream>>>((const float4*)W2, (ushort4*)W2b, 65536);

  // CSR build (group edges by dst)
  hipMemsetAsync(deg, 0, (size_t)N * 4, stream);
  k_hist<<<(E + 255) / 256, 256, 0, stream>>>(edst, E, deg);
  k_scan1<<<nb, 1024, 0, stream>>>(deg, N, rowptr, bsum);
  k_scan2<<<1, 64, 0, stream>>>(bsum, nb);
  k_scan3<<<(N + 255) / 256, 256, 0, stream>>>(rowptr, bsum, N);
  hipMemsetAsync(deg, 0, (size_t)N * 4, stream);
  k_scatter<<<(E + 255) / 256, 256, 0, stream>>>(esrc, edst, E, rowptr, deg, csr_src);

  // QKV projections
  k_qkv<<<RT64, 256, 0, stream>>>(feat, Wqb, Wkb, Wvb, bq, bk, bv, q, kk, vv, N);
  // fused segment-softmax + aggregate
  k_edge_agg<<<N, 256, 0, stream>>>(q, kk, vv, rowptr, csr_src, N, wvb);
  // x = feat + wv@Wp^T + bp ; h = LN(x) (fused)
  k_proj_ln<<<RT64, 256, 0, stream>>>(wvb, Wpb, bp, feat, x, lng, lnb, h, N);
  // out = x + gelu(h@W1^T+b1)@W2^T + b2 (fused, K-slab LDS)
  k_mlp<<<RT32, 256, 0, stream>>>(h, W1b, b1, W2b, b2, x, (float*)d_out, N);
}

// Round 6
// 1013.553 us; speedup vs baseline: 1.0165x; 1.0147x over previous
//
#include <hip/hip_runtime.h>
#include <hip/hip_bf16.h>

#define CDIM 256
#define NH 8
#define HDIM 32

typedef short bf8 __attribute__((ext_vector_type(8)));
typedef float f32x4 __attribute__((ext_vector_type(4)));

__device__ __forceinline__ float bf2f(ushort u) {
  union { unsigned int i; float f; } x; x.i = ((unsigned int)u) << 16; return x.f;
}
__device__ __forceinline__ ushort f2bf(float f) {
  union { float f; unsigned int i; } x; x.f = f;
  unsigned int lsb = (x.i >> 16) & 1u;
  unsigned int r = x.i + 0x7fffu + lsb;
  return (ushort)(r >> 16);
}

// ---------------- casts fp32 -> bf16 (vectorized) ----------------
__global__ void k_cast4(const float4* __restrict__ s, ushort4* __restrict__ d, int n4) {
  int i = blockIdx.x * blockDim.x + threadIdx.x;
  if (i < n4) {
    float4 v = s[i];
    ushort4 o;
    o.x = f2bf(v.x); o.y = f2bf(v.y); o.z = f2bf(v.z); o.w = f2bf(v.w);
    d[i] = o;
  }
}

// ---------------- CSR build ----------------
__global__ void k_hist(const int* __restrict__ dst, int E, int* __restrict__ deg) {
  int i = blockIdx.x * blockDim.x + threadIdx.x;
  if (i < E) atomicAdd(&deg[dst[i]], 1);
}

__global__ __launch_bounds__(1024) void k_scan1(const int* __restrict__ deg, int N,
                                                int* __restrict__ rowptr, int* __restrict__ bsum) {
  __shared__ int s[1024];
  int t = threadIdx.x;
  int i = blockIdx.x * 1024 + t;
  int val = (i < N) ? deg[i] : 0;
  s[t] = val;
  __syncthreads();
  for (int off = 1; off < 1024; off <<= 1) {
    int add = (t >= off) ? s[t - off] : 0;
    __syncthreads();
    s[t] += add;
    __syncthreads();
  }
  if (i < N) rowptr[i + 1] = s[t];
  if (t == 1023) bsum[blockIdx.x] = s[t];
}

__global__ void k_scan2(int* __restrict__ bsum, int nb) {
  if (threadIdx.x == 0 && blockIdx.x == 0) {
    int run = 0;
    for (int j = 0; j < nb; ++j) { int t = bsum[j]; bsum[j] = run; run += t; }
  }
}

__global__ void k_scan3(int* __restrict__ rowptr, const int* __restrict__ bsum, int N) {
  int i = blockIdx.x * blockDim.x + threadIdx.x;
  if (i < N) rowptr[i + 1] += bsum[i >> 10];
  if (i == 0) rowptr[0] = 0;
}

__global__ void k_scatter(const int* __restrict__ src, const int* __restrict__ dst, int E,
                          const int* __restrict__ rowptr, int* __restrict__ cur,
                          int* __restrict__ csr_src) {
  int i = blockIdx.x * blockDim.x + threadIdx.x;
  if (i < E) {
    int d = dst[i];
    int pos = rowptr[d] + atomicAdd(&cur[d], 1);
    csr_src[pos] = src[i];
  }
}

// ---------------- GEMM tiles (bf16 MFMA 16x16x32) ----------------
// 64x64/wave, A global row-major (row-clamped), B = W [out,in] row-major (acts B^T).
__device__ __forceinline__ void wave_tile64(const ushort* __restrict__ A, int lda, int row0, int nrows,
                                            const ushort* __restrict__ B, int ldb, int col0,
                                            int K, f32x4* acc) {
  int lane = threadIdx.x & 63;
  int m = lane & 15, quad = lane >> 4;
  const ushort* ap[4];
  const ushort* bp[4];
#pragma unroll
  for (int ri = 0; ri < 4; ++ri) {
    int r = row0 + ri * 16 + m;
    r = (r < nrows) ? r : (nrows - 1);
    ap[ri] = A + (size_t)r * lda + quad * 8;
  }
#pragma unroll
  for (int cj = 0; cj < 4; ++cj)
    bp[cj] = B + (size_t)(col0 + cj * 16 + m) * ldb + quad * 8;
  for (int k0 = 0; k0 < K; k0 += 32) {
    bf8 a[4], b[4];
#pragma unroll
    for (int ri = 0; ri < 4; ++ri) a[ri] = *(const bf8*)(ap[ri] + k0);
#pragma unroll
    for (int cj = 0; cj < 4; ++cj) b[cj] = *(const bf8*)(bp[cj] + k0);
#pragma unroll
    for (int ri = 0; ri < 4; ++ri)
#pragma unroll
      for (int cj = 0; cj < 4; ++cj)
        acc[ri * 4 + cj] = __builtin_amdgcn_mfma_f32_16x16x32_bf16(a[ri], b[cj], acc[ri * 4 + cj], 0, 0, 0);
  }
}

// 32-row variant (ri in 0..1), A global
__device__ __forceinline__ void wave_tile32g(const ushort* __restrict__ A, int lda, int row0, int nrows,
                                             const ushort* __restrict__ B, int ldb, int col0,
                                             int K, f32x4* acc) {
  int lane = threadIdx.x & 63;
  int m = lane & 15, quad = lane >> 4;
  const ushort* ap[2];
  const ushort* bp[4];
#pragma unroll
  for (int ri = 0; ri < 2; ++ri) {
    int r = row0 + ri * 16 + m;
    r = (r < nrows) ? r : (nrows - 1);
    ap[ri] = A + (size_t)r * lda + quad * 8;
  }
#pragma unroll
  for (int cj = 0; cj < 4; ++cj)
    bp[cj] = B + (size_t)(col0 + cj * 16 + m) * ldb + quad * 8;
  for (int k0 = 0; k0 < K; k0 += 32) {
    bf8 a[2], b[4];
#pragma unroll
    for (int ri = 0; ri < 2; ++ri) a[ri] = *(const bf8*)(ap[ri] + k0);
#pragma unroll
    for (int cj = 0; cj < 4; ++cj) b[cj] = *(const bf8*)(bp[cj] + k0);
#pragma unroll
    for (int ri = 0; ri < 2; ++ri)
#pragma unroll
      for (int cj = 0; cj < 4; ++cj)
        acc[ri * 4 + cj] = __builtin_amdgcn_mfma_f32_16x16x32_bf16(a[ri], b[cj], acc[ri * 4 + cj], 0, 0, 0);
  }
}

// ---------------- m93-style block-tiled GEMM: 128x128 tile, BK=32, LDS-staged A and B ----
// A [M x lda] row-major bf16 (row-clamped), B = W [out x lda] row-major bf16.
// Each of 4 waves computes a 64x64 quadrant: 16 MFMA : 8 ds_read_b128 per k-step.
// Global loads for step k are issued before the barrier ending step k-1's compute.
struct GemmAcc { f32x4 a[16]; };

__device__ __forceinline__ void block_gemm128(const ushort* __restrict__ A, int lda, int row0, int nrows,
                                              const ushort* __restrict__ B, int col0,
                                              int K, ushort* sA, ushort* sB, f32x4* acc) {
  int t = threadIdx.x;
  int lane = t & 63, m = lane & 15, quad = lane >> 4, wave = t >> 6;
  int wr = (wave >> 1) * 64, wc = (wave & 1) * 64;
  // staging roles: granules g0=t, g1=t+256 of 512 (row = g>>2, 16B col-group = g&3)
  int g0 = t, g1 = t + 256;
  int ar0 = g0 >> 2, ac0 = (g0 & 3) * 8;
  int ar1 = g1 >> 2, ac1 = (g1 & 3) * 8;
  int arow0 = (row0 + ar0 < nrows) ? row0 + ar0 : nrows - 1;
  int arow1 = (row0 + ar1 < nrows) ? row0 + ar1 : nrows - 1;
  const ushort* Ap0 = A + (size_t)arow0 * lda + ac0;
  const ushort* Ap1 = A + (size_t)arow1 * lda + ac1;
  const ushort* Bp0 = B + (size_t)(col0 + ar0) * lda + ac0;
  const ushort* Bp1 = B + (size_t)(col0 + ar1) * lda + ac1;

  for (int k0 = 0; k0 < K; k0 += 32) {
    uint4 va0 = *(const uint4*)(Ap0 + k0);
    uint4 va1 = *(const uint4*)(Ap1 + k0);
    uint4 vb0 = *(const uint4*)(Bp0 + k0);
    uint4 vb1 = *(const uint4*)(Bp1 + k0);
    __syncthreads();  // previous step's ds_reads done
    *(uint4*)&sA[ar0 * 32 + ac0] = va0;
    *(uint4*)&sA[ar1 * 32 + ac1] = va1;
    *(uint4*)&sB[ar0 * 32 + ac0] = vb0;
    *(uint4*)&sB[ar1 * 32 + ac1] = vb1;
    __syncthreads();
    bf8 fa[4], fb[4];
#pragma unroll
    for (int ri = 0; ri < 4; ++ri) fa[ri] = *(const bf8*)&sA[(wr + ri * 16 + m) * 32 + quad * 8];
#pragma unroll
    for (int cj = 0; cj < 4; ++cj) fb[cj] = *(const bf8*)&sB[(wc + cj * 16 + m) * 32 + quad * 8];
#pragma unroll
    for (int ri = 0; ri < 4; ++ri)
#pragma unroll
      for (int cj = 0; cj < 4; ++cj)
        acc[ri * 4 + cj] = __builtin_amdgcn_mfma_f32_16x16x32_bf16(fa[ri], fb[cj], acc[ri * 4 + cj], 0, 0, 0);
  }
}

// hid = gelu(h @ W1^T + b1) : [N x 1024]
__global__ __launch_bounds__(256) void k_gemm1(const ushort* __restrict__ h,
                                               const ushort* __restrict__ W1,
                                               const float* __restrict__ b1,
                                               ushort* __restrict__ hid, int N) {
  __shared__ ushort sA[128 * 32];
  __shared__ ushort sB[128 * 32];
  int row0 = blockIdx.x * 128, col0 = blockIdx.y * 128;
  f32x4 acc[16];
#pragma unroll
  for (int j = 0; j < 16; ++j) acc[j] = (f32x4){0.f, 0.f, 0.f, 0.f};
  block_gemm128(h, CDIM, row0, N, W1, col0, CDIM, sA, sB, acc);

  int lane = threadIdx.x & 63, m = lane & 15, quad = lane >> 4, wave = threadIdx.x >> 6;
  int wr = (wave >> 1) * 64, wc = (wave & 1) * 64;
#pragma unroll
  for (int cj = 0; cj < 4; ++cj) {
    int cc = col0 + wc + cj * 16 + m;
    float bs = b1[cc];
#pragma unroll
    for (int ri = 0; ri < 4; ++ri)
#pragma unroll
      for (int i = 0; i < 4; ++i) {
        int r = row0 + wr + ri * 16 + quad * 4 + i;
        if (r < N) {
          float tt = acc[ri * 4 + cj][i] + bs;
          float gl = 0.5f * tt * (1.f + erff(tt * 0.70710678118654752f));
          hid[(size_t)r * 1024 + cc] = f2bf(gl);
        }
      }
  }
}

// out = x + hid @ W2^T + b2 : [N x 256] fp32
__global__ __launch_bounds__(256) void k_gemm2(const ushort* __restrict__ hid,
                                               const ushort* __restrict__ W2,
                                               const float* __restrict__ b2,
                                               const float* __restrict__ x,
                                               float* __restrict__ out, int N) {
  __shared__ ushort sA[128 * 32];
  __shared__ ushort sB[128 * 32];
  int row0 = blockIdx.x * 128, col0 = blockIdx.y * 128;
  f32x4 acc[16];
#pragma unroll
  for (int j = 0; j < 16; ++j) acc[j] = (f32x4){0.f, 0.f, 0.f, 0.f};
  block_gemm128(hid, 1024, row0, N, W2, col0, 1024, sA, sB, acc);

  int lane = threadIdx.x & 63, m = lane & 15, quad = lane >> 4, wave = threadIdx.x >> 6;
  int wr = (wave >> 1) * 64, wc = (wave & 1) * 64;
#pragma unroll
  for (int cj = 0; cj < 4; ++cj) {
    int cc = col0 + wc + cj * 16 + m;
    float bs = b2[cc];
#pragma unroll
    for (int ri = 0; ri < 4; ++ri)
#pragma unroll
      for (int i = 0; i < 4; ++i) {
        int r = row0 + wr + ri * 16 + quad * 4 + i;
        if (r < N) out[(size_t)r * CDIM + cc] = x[(size_t)r * CDIM + cc] + acc[ri * 4 + cj][i] + bs;
      }
  }
}

// q,k,v for 64 rows per block; feat (fp32) staged once into XOR-swizzled LDS as bf16.
__global__ __launch_bounds__(256) void k_qkv(const float* __restrict__ feat,
                                             const ushort* __restrict__ Wq, const ushort* __restrict__ Wk,
                                             const ushort* __restrict__ Wv,
                                             const float* __restrict__ bq, const float* __restrict__ bk,
                                             const float* __restrict__ bv,
                                             ushort* __restrict__ q, ushort* __restrict__ k,
                                             ushort* __restrict__ v, int N) {
  __shared__ ushort sa[64 * 256];  // 32 KB
  int rt = blockIdx.x, row0 = rt * 64;
#pragma unroll
  for (int s = 0; s < 8; ++s) {
    int c = threadIdx.x + s * 256;
    int row = c >> 5, g = c & 31;
    int r = row0 + row; r = (r < N) ? r : (N - 1);
    const float* fp = feat + (size_t)r * CDIM + g * 8;
    float4 x0 = *(const float4*)fp;
    float4 x1 = *(const float4*)(fp + 4);
    union { ushort us[8]; uint4 v; } pk;
    pk.us[0] = f2bf(x0.x); pk.us[1] = f2bf(x0.y); pk.us[2] = f2bf(x0.z); pk.us[3] = f2bf(x0.w);
    pk.us[4] = f2bf(x1.x); pk.us[5] = f2bf(x1.y); pk.us[6] = f2bf(x1.z); pk.us[7] = f2bf(x1.w);
    *(uint4*)&sa[row * 256 + ((g ^ (row & 7)) << 3)] = pk.v;
  }
  __syncthreads();

  int wave = threadIdx.x >> 6, lane = threadIdx.x & 63, m = lane & 15, quad = lane >> 4;
  int col0 = wave * 64;
  for (int which = 0; which < 3; ++which) {
    const ushort* W = (which == 0) ? Wq : (which == 1) ? Wk : Wv;
    const float* bias = (which == 0) ? bq : (which == 1) ? bk : bv;
    ushort* outp = (which == 0) ? q : (which == 1) ? k : v;
    f32x4 acc[16];
#pragma unroll
    for (int j = 0; j < 16; ++j) acc[j] = (f32x4){0.f, 0.f, 0.f, 0.f};
    const ushort* bp[4];
#pragma unroll
    for (int cj = 0; cj < 4; ++cj)
      bp[cj] = W + (size_t)(col0 + cj * 16 + m) * CDIM + quad * 8;
    for (int k0 = 0; k0 < CDIM; k0 += 32) {
      int sw = ((((k0 >> 3) + quad) ^ (m & 7)) << 3);
      bf8 a[4], b[4];
#pragma unroll
      for (int ri = 0; ri < 4; ++ri) a[ri] = *(const bf8*)&sa[(ri * 16 + m) * 256 + sw];
#pragma unroll
      for (int cj = 0; cj < 4; ++cj) b[cj] = *(const bf8*)(bp[cj] + k0);
#pragma unroll
      for (int ri = 0; ri < 4; ++ri)
#pragma unroll
        for (int cj = 0; cj < 4; ++cj)
          acc[ri * 4 + cj] = __builtin_amdgcn_mfma_f32_16x16x32_bf16(a[ri], b[cj], acc[ri * 4 + cj], 0, 0, 0);
    }
#pragma unroll
    for (int cj = 0; cj < 4; ++cj) {
      int cc = col0 + cj * 16 + m;
      float bs = bias[cc];
#pragma unroll
      for (int ri = 0; ri < 4; ++ri)
#pragma unroll
        for (int i = 0; i < 4; ++i) {
          int r = row0 + ri * 16 + quad * 4 + i;
          if (r < N) outp[(size_t)r * CDIM + cc] = f2bf(acc[ri * 4 + cj][i] + bs);
        }
    }
  }
}

// fused segment softmax + aggregate (unchanged)
__global__ __launch_bounds__(256) void k_edge_agg(const ushort* __restrict__ q,
                                                  const ushort* __restrict__ kk,
                                                  const ushort* __restrict__ vv,
                                                  const int* __restrict__ rowptr,
                                                  const int* __restrict__ csr_src,
                                                  int N,
                                                  ushort* __restrict__ wv) {
  __shared__ float e_T[8 * 36];
  __shared__ int srcs[32];
  __shared__ float wdens[32];

  int n = blockIdx.x;
  int t = threadIdx.x;
  int lane = t & 63, wave = t >> 6;
  int el = t >> 3, h = t & 7;
  int h2 = t >> 5;

  int beg = rowptr[n], end = rowptr[n + 1];
  int deg = end - beg;

  float qf[32];
  {
    const ushort* qp = q + (size_t)n * CDIM + h * HDIM;
#pragma unroll
    for (int g = 0; g < 4; ++g) {
      bf8 qv = *(const bf8*)(qp + g * 8);
#pragma unroll
      for (int j = 0; j < 8; ++j) qf[g * 8 + j] = bf2f((ushort)qv[j]);
    }
  }

  float accv = 0.f;
  float den_part = 0.f;

  int nch = (deg + 31) >> 5;
  for (int ch = 0; ch < nch; ++ch) {
    int eidx = beg + ch * 32 + el;
    int src = 0;
    float e = 0.f;
    if (eidx < end) {
      src = csr_src[eidx];
      const ushort* kp = kk + (size_t)src * CDIM + h * HDIM;
      float dot = 0.f;
#pragma unroll
      for (int g = 0; g < 4; ++g) {
        bf8 kv = *(const bf8*)(kp + g * 8);
#pragma unroll
        for (int j = 0; j < 8; ++j) dot = fmaf(qf[g * 8 + j], bf2f((ushort)kv[j]), dot);
      }
      float s = dot * 0.17677669529663687f;
      s = fminf(10.f, fmaxf(-10.f, s));
      e = __expf(s - 10.f);
    }
    e_T[h * 36 + el] = e;
    if (h == 0) srcs[el] = src;
    den_part += e;
    __syncthreads();

#pragma unroll
    for (int g4 = 0; g4 < 8; ++g4) {
      int4 s4 = *(const int4*)&srcs[g4 * 4];
      float4 e4 = *(const float4*)&e_T[h2 * 36 + g4 * 4];
      accv = fmaf(e4.x, bf2f(vv[(size_t)s4.x * CDIM + t]), accv);
      accv = fmaf(e4.y, bf2f(vv[(size_t)s4.y * CDIM + t]), accv);
      accv = fmaf(e4.z, bf2f(vv[(size_t)s4.z * CDIM + t]), accv);
      accv = fmaf(e4.w, bf2f(vv[(size_t)s4.w * CDIM + t]), accv);
    }
    __syncthreads();
  }

  float d = den_part;
  d += __shfl_xor(d, 8);
  d += __shfl_xor(d, 16);
  d += __shfl_xor(d, 32);
  if (lane < 8) wdens[wave * 8 + lane] = d;
  __syncthreads();
  float den = wdens[h2] + wdens[8 + h2] + wdens[16 + h2] + wdens[24 + h2];
  wv[(size_t)n * CDIM + t] = f2bf((deg > 0) ? accv / den : 0.f);
}

// x = feat + wv@Wp^T + bp, then h = LN(x)*g + b, fused (block owns 64 rows x 256 cols)
__global__ __launch_bounds__(256) void k_proj_ln(const ushort* __restrict__ wv,
                                                 const ushort* __restrict__ Wp,
                                                 const float* __restrict__ bp,
                                                 const float* __restrict__ feat,
                                                 float* __restrict__ x,
                                                 const float* __restrict__ lng,
                                                 const float* __restrict__ lnb,
                                                 ushort* __restrict__ h, int N) {
  __shared__ float red_s[64 * 4];
  __shared__ float red_ss[64 * 4];
  __shared__ float stats[64 * 2];
  int rt = blockIdx.x;
  int wave = threadIdx.x >> 6, lane = threadIdx.x & 63, m = lane & 15, quad = lane >> 4;
  int row0 = rt * 64, col0 = wave * 64;
  f32x4 acc[16];
#pragma unroll
  for (int j = 0; j < 16; ++j) acc[j] = (f32x4){0.f, 0.f, 0.f, 0.f};
  wave_tile64(wv, CDIM, row0, N, Wp, CDIM, col0, CDIM, acc);

  float s1[4][4], s2[4][4];
#pragma unroll
  for (int ri = 0; ri < 4; ++ri)
#pragma unroll
    for (int i = 0; i < 4; ++i) { s1[ri][i] = 0.f; s2[ri][i] = 0.f; }

#pragma unroll
  for (int cj = 0; cj < 4; ++cj) {
    int cc = col0 + cj * 16 + m;
    float bs = bp[cc];
#pragma unroll
    for (int ri = 0; ri < 4; ++ri)
#pragma unroll
      for (int i = 0; i < 4; ++i) {
        int r = row0 + ri * 16 + quad * 4 + i;
        if (r < N) {
          float val = acc[ri * 4 + cj][i] + bs + feat[(size_t)r * CDIM + cc];
          acc[ri * 4 + cj][i] = val;
          x[(size_t)r * CDIM + cc] = val;
          s1[ri][i] += val;
          s2[ri][i] += val * val;
        }
      }
  }
#pragma unroll
  for (int msk = 1; msk <= 8; msk <<= 1) {
#pragma unroll
    for (int ri = 0; ri < 4; ++ri)
#pragma unroll
      for (int i = 0; i < 4; ++i) {
        s1[ri][i] += __shfl_xor(s1[ri][i], msk);
        s2[ri][i] += __shfl_xor(s2[ri][i], msk);
      }
  }
  if (m == 0) {
#pragma unroll
    for (int ri = 0; ri < 4; ++ri)
#pragma unroll
      for (int i = 0; i < 4; ++i) {
        int lr = ri * 16 + quad * 4 + i;
        red_s[lr * 4 + wave] = s1[ri][i];
        red_ss[lr * 4 + wave] = s2[ri][i];
      }
  }
  __syncthreads();
  if (threadIdx.x < 64) {
    int lr = threadIdx.x;
    float s = red_s[lr * 4] + red_s[lr * 4 + 1] + red_s[lr * 4 + 2] + red_s[lr * 4 + 3];
    float ss = red_ss[lr * 4] + red_ss[lr * 4 + 1] + red_ss[lr * 4 + 2] + red_ss[lr * 4 + 3];
    float mu = s * (1.f / CDIM);
    float var = ss * (1.f / CDIM) - mu * mu;
    stats[lr * 2] = mu;
    stats[lr * 2 + 1] = rsqrtf(var + 1e-5f);
  }
  __syncthreads();
#pragma unroll
  for (int cj = 0; cj < 4; ++cj) {
    int cc = col0 + cj * 16 + m;
    float ga = lng[cc], be = lnb[cc];
#pragma unroll
    for (int ri = 0; ri < 4; ++ri)
#pragma unroll
      for (int i = 0; i < 4; ++i) {
        int lr = ri * 16 + quad * 4 + i;
        int r = row0 + lr;
        if (r < N) {
          float mu = stats[lr * 2], rs = stats[lr * 2 + 1];
          h[(size_t)r * CDIM + cc] = f2bf((acc[ri * 4 + cj][i] - mu) * rs * ga + be);
        }
      }
  }
}

// fallback fused MLP (round-5 K-slab version) for small workspaces
__global__ __launch_bounds__(256) void k_mlp(const ushort* __restrict__ h,
                                             const ushort* __restrict__ W1,
                                             const float* __restrict__ b1,
                                             const ushort* __restrict__ W2,
                                             const float* __restrict__ b2,
                                             const float* __restrict__ x,
                                             float* __restrict__ out, int N) {
  __shared__ ushort sh[32 * 256];  // 16 KB
  int rt = blockIdx.x;
  int row0 = rt * 32;
  int wave = threadIdx.x >> 6, lane = threadIdx.x & 63, m = lane & 15, quad = lane >> 4;

  int col0 = wave * 64;
  f32x4 acc2[8];
#pragma unroll
  for (int j = 0; j < 8; ++j) acc2[j] = (f32x4){0.f, 0.f, 0.f, 0.f};
  const ushort* bp2[4];
#pragma unroll
  for (int cj = 0; cj < 4; ++cj)
    bp2[cj] = W2 + (size_t)(col0 + cj * 16 + m) * 1024 + quad * 8;

  for (int slab = 0; slab < 4; ++slab) {
    int hcol0 = slab * 256 + wave * 64;
    f32x4 acc1[8];
#pragma unroll
    for (int j = 0; j < 8; ++j) acc1[j] = (f32x4){0.f, 0.f, 0.f, 0.f};
    wave_tile32g(h, CDIM, row0, N, W1, CDIM, hcol0, CDIM, acc1);
#pragma unroll
    for (int cj = 0; cj < 4; ++cj) {
      int ccl = wave * 64 + cj * 16 + m;
      float bs = b1[slab * 256 + ccl];
#pragma unroll
      for (int ri = 0; ri < 2; ++ri)
#pragma unroll
        for (int i = 0; i < 4; ++i) {
          int lr = ri * 16 + quad * 4 + i;
          float tt = acc1[ri * 4 + cj][i] + bs;
          float gl = 0.5f * tt * (1.f + erff(tt * 0.70710678118654752f));
          int sc = ((((ccl >> 3) ^ (lr & 7)) << 3) | (ccl & 7));
          sh[lr * 256 + sc] = f2bf(gl);
        }
    }
    __syncthreads();

    for (int k0 = 0; k0 < 256; k0 += 32) {
      int g = (k0 >> 3) + quad;
      bf8 a[2], b[4];
#pragma unroll
      for (int ri = 0; ri < 2; ++ri)
        a[ri] = *(const bf8*)&sh[(ri * 16 + m) * 256 + ((g ^ (m & 7)) << 3)];
#pragma unroll
      for (int cj = 0; cj < 4; ++cj) b[cj] = *(const bf8*)(bp2[cj] + slab * 256 + k0);
#pragma unroll
      for (int ri = 0; ri < 2; ++ri)
#pragma unroll
        for (int cj = 0; cj < 4; ++cj)
          acc2[ri * 4 + cj] = __builtin_amdgcn_mfma_f32_16x16x32_bf16(a[ri], b[cj], acc2[ri * 4 + cj], 0, 0, 0);
    }
    __syncthreads();
  }

#pragma unroll
  for (int cj = 0; cj < 4; ++cj) {
    int cc = col0 + cj * 16 + m;
    float bs = b2[cc];
#pragma unroll
    for (int ri = 0; ri < 2; ++ri)
#pragma unroll
      for (int i = 0; i < 4; ++i) {
        int r = row0 + ri * 16 + quad * 4 + i;
        if (r < N) out[(size_t)r * CDIM + cc] = x[(size_t)r * CDIM + cc] + acc2[ri * 4 + cj][i] + bs;
      }
  }
}

extern "C" void kernel_launch(void* const* d_in, const int* in_sizes, int n_in,
                              void* d_out, int out_size, void* d_ws, size_t ws_size,
                              hipStream_t stream) {
  const float* feat = (const float*)d_in[0];
  const int* esrc = (const int*)d_in[1];
  const int* edst = (const int*)d_in[2];
  const float* Wq = (const float*)d_in[3];
  const float* bq = (const float*)d_in[4];
  const float* Wk = (const float*)d_in[5];
  const float* bk = (const float*)d_in[6];
  const float* Wv = (const float*)d_in[7];
  const float* bv = (const float*)d_in[8];
  const float* Wp = (const float*)d_in[9];
  const float* bp = (const float*)d_in[10];
  const float* lng = (const float*)d_in[11];
  const float* lnb = (const float*)d_in[12];
  const float* W1 = (const float*)d_in[13];
  const float* b1 = (const float*)d_in[14];
  const float* W2 = (const float*)d_in[15];
  const float* b2 = (const float*)d_in[16];

  const int N = in_sizes[0] / CDIM;  // 50000
  const int E = in_sizes[1];         // 1600000
  const size_t NC2 = (size_t)N * CDIM * 2;  // bf16 plane: 25.6 MB

  char* w = (char*)d_ws;
  ushort* q   = (ushort*)(w);
  ushort* kk  = (ushort*)(w + NC2);
  ushort* vv  = (ushort*)(w + 2 * NC2);
  ushort* wvb = (ushort*)(w + 3 * NC2);
  float*  x   = (float*)(w);               // overlays q+k (dead after edge_agg)
  ushort* h   = (ushort*)(w + 2 * NC2);    // overlays v (dead after edge_agg)

  char* csr = w + 4 * NC2;
  int* rowptr  = (int*)(csr);
  int* deg     = (int*)(csr + 200064);
  int* csr_src = (int*)(csr + 400128);
  int* bsum    = (int*)(csr + 400128 + (size_t)E * 4);

  char* wb = csr + 400128 + (size_t)E * 4 + 256;
  ushort* Wqb = (ushort*)(wb);
  ushort* Wkb = (ushort*)(wb + 131072);
  ushort* Wvb = (ushort*)(wb + 262144);
  ushort* Wpb = (ushort*)(wb + 393216);
  ushort* W1b = (ushort*)(wb + 524288);
  ushort* W2b = (ushort*)(wb + 1048576);

  // hid (N x 1024 bf16) lives after everything else; only if ws_size permits
  size_t hid_off = ((size_t)(wb - w) + 1572864 + 255) & ~(size_t)255;
  size_t need_full = hid_off + (size_t)N * 1024 * 2;
  bool full_path = (ws_size >= need_full);
  ushort* hid = (ushort*)(w + hid_off);

  const int nb = (N + 1023) / 1024;
  const int RT64 = (N + 63) / 64;    // 782
  const int RT32 = (N + 31) / 32;    // 1563
  const int RT128 = (N + 127) / 128; // 391

  // weight casts
  k_cast4<<<(16384 + 255) / 256, 256, 0, stream>>>((const float4*)Wq, (ushort4*)Wqb, 16384);
  k_cast4<<<(16384 + 255) / 256, 256, 0, stream>>>((const float4*)Wk, (ushort4*)Wkb, 16384);
  k_cast4<<<(16384 + 255) / 256, 256, 0, stream>>>((const float4*)Wv, (ushort4*)Wvb, 16384);
  k_cast4<<<(16384 + 255) / 256, 256, 0, stream>>>((const float4*)Wp, (ushort4*)Wpb, 16384);
  k_cast4<<<(65536 + 255) / 256, 256, 0, stream>>>((const float4*)W1, (ushort4*)W1b, 65536);
  k_cast4<<<(65536 + 255) / 256, 256, 0, stream>>>((const float4*)W2, (ushort4*)W2b, 65536);

  // CSR build (group edges by dst)
  hipMemsetAsync(deg, 0, (size_t)N * 4, stream);
  k_hist<<<(E + 255) / 256, 256, 0, stream>>>(edst, E, deg);
  k_scan1<<<nb, 1024, 0, stream>>>(deg, N, rowptr, bsum);
  k_scan2<<<1, 64, 0, stream>>>(bsum, nb);
  k_scan3<<<(N + 255) / 256, 256, 0, stream>>>(rowptr, bsum, N);
  hipMemsetAsync(deg, 0, (size_t)N * 4, stream);
  k_scatter<<<(E + 255) / 256, 256, 0, stream>>>(esrc, edst, E, rowptr, deg, csr_src);

  // QKV projections
  k_qkv<<<RT64, 256, 0, stream>>>(feat, Wqb, Wkb, Wvb, bq, bk, bv, q, kk, vv, N);
  // fused segment-softmax + aggregate
  k_edge_agg<<<N, 256, 0, stream>>>(q, kk, vv, rowptr, csr_src, N, wvb);
  // x = feat + wv@Wp^T + bp ; h = LN(x) (fused)
  k_proj_ln<<<RT64, 256, 0, stream>>>(wvb, Wpb, bp, feat, x, lng, lnb, h, N);

  if (full_path) {
    // hid = gelu(h@W1^T + b1) ; out = x + hid@W2^T + b2  (m93-style tiled GEMMs)
    k_gemm1<<<dim3(RT128, 8), 256, 0, stream>>>(h, W1b, b1, hid, N);
    k_gemm2<<<dim3(RT128, 2), 256, 0, stream>>>(hid, W2b, b2, x, (float*)d_out, N);
  } else {
    k_mlp<<<RT32, 256, 0, stream>>>(h, W1b, b1, W2b, b2, x, (float*)d_out, N);
  }
}